// Round 5
// baseline (4500.308 us; speedup 1.0000x reference)
//
#include <hip/hip_runtime.h>
#include <cmath>

#define B_ 64
#define NP 512   // N == M == 512, D == 2

constexpr float L2E  = 1.4426950408889634f;   // log2(e)
constexpr float LN2f = 0.6931471805599453f;

struct EpsList { float e[64]; };

__device__ __forceinline__ float exp2_fast(float v) {
#if __has_builtin(__builtin_amdgcn_exp2f)
    return __builtin_amdgcn_exp2f(v);
#else
    return exp2f(v);
#endif
}
__device__ __forceinline__ float log2_fast(float v) {
#if __has_builtin(__builtin_amdgcn_logf)
    return __builtin_amdgcn_logf(v);
#else
    return log2f(v);
#endif
}

// Cooperative kernel, 512 blocks = B_ x 8, 256 threads (2 blocks/CU — the
// geometry round 3 PROVED co-resident). Block (b, q): q<4 -> f-side (rows over
// x, reduce over y), q>=4 -> g-side. rq = q&3 selects a 128-row quarter.
// Thread layout: oct = tid&7 owns j = oct (mod 8); tid>>3 owns 4 consecutive
// rows; one float4 LDS broadcast read serves 4 rows (conflict-free, proven R2).
//
// Buffers: pure pass-parity. Writes of pass p go to buffer (p&1); reads of
// pass p (p>=1) come from buffer ((p-1)&1). No mutable toggle state.
//
// Cross-block sync: per-batch monotonic semaphore (8 signals per pass) —
// batches never wait on each other, so sync latency pipelines across batches.
// A block signals only after its reads AND writes of the pass are complete
// (__syncthreads drains them), so one barrier per pass is race-free.
__global__ __launch_bounds__(256, 2) void sinkhorn_coop(
    const float* __restrict__ a, const float* __restrict__ x,
    const float* __restrict__ bb, const float* __restrict__ y,
    float* __restrict__ fA, float* __restrict__ gA,
    float* __restrict__ fB, float* __restrict__ gB,
    unsigned int* __restrict__ bar, float* __restrict__ part2,
    EpsList el, int n_eps)
{
    __shared__ float4 sreg[NP];   // {cx, cy, |c|^2, log2-weight} (pass-invariant)
    __shared__ float4 sd[NP];     // {cx, cy, shp, 0} (rebuilt per pass)
    __shared__ float s_eps[64];
    __shared__ float swred[4];

    const int bid = blockIdx.x;
    const int b   = bid >> 3;
    const int q   = bid & 7;
    const bool gside = q >= 4;
    const int rq  = q & 3;
    const int tid = threadIdx.x;
    const int oct = tid & 7;
    const int rowbase = rq * 128 + (tid >> 3) * 4;
    unsigned int* mybar = bar + b * 32;   // one 128B-padded counter per batch

    if (tid < 64) s_eps[tid] = el.e[tid];

    // ---- one-time staging ----
    // reduced-over side: 2 points per thread into LDS
    const float2* oc2   = (const float2*)(gside ? (x + b * NP * 2) : (y + b * NP * 2));
    const float*  oprob = gside ? (a + b * NP) : (bb + b * NP);
    #pragma unroll
    for (int u2 = 0; u2 < 2; ++u2) {
        int t = tid + u2 * 256;
        float2 c = oc2[t];
        sreg[t] = make_float4(c.x, c.y, fmaf(c.y, c.y, c.x * c.x),
                              L2E * logf(oprob[t]));
    }
    // row side: 4 rows per thread into registers
    const float* mcoord = gside ? (y + b * NP * 2) : (x + b * NP * 2);
    const float* mprob  = gside ? (bb + b * NP)    : (a + b * NP);
    const float4 rc01 = *(const float4*)(mcoord + rowbase * 2);
    const float4 rc23 = *(const float4*)(mcoord + rowbase * 2 + 4);
    float x0[4] = {rc01.x, rc01.z, rc23.x, rc23.z};
    float x1[4] = {rc01.y, rc01.w, rc23.y, rc23.w};
    float half_n2[4];
    #pragma unroll
    for (int r = 0; r < 4; ++r) half_n2[r] = 0.5f * fmaf(x1[r], x1[r], x0[r] * x0[r]);

    float pv[4];
    const int n_pass = n_eps + 2;
    __syncthreads();

    for (int p = 0; p < n_pass; ++p) {
        const float eps = (p == 0) ? s_eps[0]
                        : (p <= n_eps ? s_eps[p - 1] : s_eps[n_eps - 1]);
        const float inv_eps = 1.0f / eps;
        const float ieL2E = inv_eps * L2E;
        const float nie   = -0.5f * ieL2E;

        // rebuild shp for the reduced-over side; other-side potential of pass
        // p-1 lives in buffer ((p-1)&1): A if p odd, B if p even.
        const float* opot = (gside ? ((p & 1) ? fA : fB)
                                   : ((p & 1) ? gA : gB)) + b * NP;
        #pragma unroll
        for (int u2 = 0; u2 < 2; ++u2) {
            int t = tid + u2 * 256;
            float4 sr = sreg[t];
            float h2 = sr.w;
            if (p != 0) h2 = fmaf(opot[t], ieL2E, h2);
            sd[t] = make_float4(sr.x, sr.y, fmaf(nie, sr.z, h2), 0.0f);
        }
        __syncthreads();

        float x0p[4], x1p[4], m[4], s[4];
        #pragma unroll
        for (int r = 0; r < 4; ++r) {
            x0p[r] = x0[r] * ieL2E;
            x1p[r] = x1[r] * ieL2E;
            m[r] = -INFINITY;
            s[r] = 0.0f;
        }

        #pragma unroll 1
        for (int k = 0; k < 8; ++k) {
            float4 cj[8];
            #pragma unroll
            for (int u2 = 0; u2 < 8; ++u2) cj[u2] = sd[64 * k + 8 * u2 + oct];
            #pragma unroll
            for (int r = 0; r < 4; ++r) {
                float arg[8];
                #pragma unroll
                for (int u2 = 0; u2 < 8; ++u2)
                    arg[u2] = fmaf(x1p[r], cj[u2].y, fmaf(x0p[r], cj[u2].x, cj[u2].z));
                float cm = fmaxf(fmaxf(fmaxf(arg[0], arg[1]), fmaxf(arg[2], arg[3])),
                                 fmaxf(fmaxf(arg[4], arg[5]), fmaxf(arg[6], arg[7])));
                float mn = fmaxf(m[r], cm);
                s[r] *= exp2_fast(m[r] - mn);   // first chunk: exp2(-inf)=0
                #pragma unroll
                for (int u2 = 0; u2 < 8; ++u2) s[r] += exp2_fast(arg[u2] - mn);
                m[r] = mn;
            }
        }

        // combine the 8 octants via butterfly (all lanes end with the result)
        float val[4];
        #pragma unroll
        for (int r = 0; r < 4; ++r) {
            float mr = m[r], sr = s[r];
            #pragma unroll
            for (int d = 1; d <= 4; d <<= 1) {
                float mo = __shfl_xor(mr, d);
                float so = __shfl_xor(sr, d);
                float mt = fmaxf(mr, mo);
                sr = sr * exp2_fast(mr - mt) + so * exp2_fast(mo - mt);
                mr = mt;
            }
            val[r] = fmaf(-eps * LN2f, mr + log2_fast(sr), half_n2[r]);
        }

        if (p >= 1 && p <= n_eps) {
            #pragma unroll
            for (int r = 0; r < 4; ++r) val[r] = 0.5f * (pv[r] + val[r]);
        }
        #pragma unroll
        for (int r = 0; r < 4; ++r) pv[r] = val[r];

        if (p == n_pass - 1) break;   // final extrapolation: no write, no barrier

        if (oct == 0) {
            float* dst = (gside ? ((p & 1) ? gB : gA)
                                : ((p & 1) ? fB : fA)) + b * NP;
            *(float4*)(dst + rowbase) = make_float4(val[0], val[1], val[2], val[3]);
        }

        // ---- per-batch barrier (8 participants) ----
        __syncthreads();        // all waves' reads of sd & writes drained
        __threadfence();        // agent release: L2 writeback for cross-XCD
        if (tid == 0) {
            __hip_atomic_fetch_add(mybar, 1u, __ATOMIC_RELEASE, __HIP_MEMORY_SCOPE_AGENT);
            const unsigned int target = 8u * (unsigned int)(p + 1);
            unsigned int guard = 0;
            while (__hip_atomic_load(mybar, __ATOMIC_ACQUIRE, __HIP_MEMORY_SCOPE_AGENT) < target) {
                __builtin_amdgcn_s_sleep(2);
                if (++guard > (1u << 22)) break;   // safety valve (never hit if resident)
            }
        }
        __syncthreads();
        __threadfence();        // agent acquire: invalidate stale lines
    }

    // ---- fused weighted dot product of the final extrapolated potentials ----
    float local = 0.0f;
    if (oct == 0) {
        const float4 pr = *(const float4*)(mprob + rowbase);
        local = pr.x * pv[0] + pr.y * pv[1] + pr.z * pv[2] + pr.w * pv[3];
    }
    #pragma unroll
    for (int o = 32; o > 0; o >>= 1) local += __shfl_down(local, o);
    if ((tid & 63) == 0) swred[tid >> 6] = local;
    __syncthreads();
    if (tid == 0) part2[bid] = swred[0] + swred[1] + swred[2] + swred[3];
}

// Deterministic final reduction: out = sum_b w[b] * sum_q part2[b*8+q]
__global__ void finred_k(const float* __restrict__ part2,
                         const float* __restrict__ w, float* __restrict__ out) {
    int b = threadIdx.x;   // 64 threads, one wave
    float s = 0.0f;
    #pragma unroll
    for (int u = 0; u < 8; ++u) s += part2[b * 8 + u];
    s *= w[b];
    #pragma unroll
    for (int o = 32; o > 0; o >>= 1) s += __shfl_down(s, o);
    if (b == 0) out[0] = s;
}

extern "C" void kernel_launch(void* const* d_in, const int* in_sizes, int n_in,
                              void* d_out, int out_size, void* d_ws, size_t ws_size,
                              hipStream_t stream) {
    const float* a  = (const float*)d_in[0];  // prob1   [B,N]
    const float* x  = (const float*)d_in[1];  // coord1  [B,N,2]
    const float* bb = (const float*)d_in[2];  // prob2   [B,M]
    const float* y  = (const float*)d_in[3];  // coord2  [B,M,2]
    const float* w  = (const float*)d_in[4];  // weights [B]
    float* out = (float*)d_out;

    // workspace layout
    unsigned char* wsb = (unsigned char*)d_ws;
    unsigned int* bar = (unsigned int*)wsb;              // 64 counters, 128B apart
    float* part2 = (float*)(wsb + 64 * 32 * 4);          // 512 floats
    float* fA = (float*)(wsb + 64 * 32 * 4 + 512 * 4);
    const int NB = B_ * NP;
    float* gA = fA + NB;
    float* fB = gA + NB;
    float* gB = fB + NB;

    // eps schedule (geomloss epsilon_schedule semantics, computed in double)
    EpsList el{};
    int n_eps = 0;
    {
        const double start = 2.0 * std::log(4.0);
        const double stop  = 2.0 * std::log(0.01);
        const double step  = 2.0 * std::log(0.9);
        el.e[n_eps++] = 16.0f;                     // DIAMETER**P
        for (int k = 0;; ++k) {
            double v = start + (double)k * step;
            if (!(v > stop)) break;
            el.e[n_eps++] = (float)std::exp(v);
        }
        el.e[n_eps++] = (float)(0.01 * 0.01);      // BLUR**P
    }

    // semaphores must restart from 0 on every call (and ws is poisoned once)
    hipMemsetAsync(bar, 0, 64 * 32 * 4 + 512 * 4, stream);

    void* args[] = {
        (void*)&a, (void*)&x, (void*)&bb, (void*)&y,
        (void*)&fA, (void*)&gA, (void*)&fB, (void*)&gB,
        (void*)&bar, (void*)&part2, (void*)&el, (void*)&n_eps
    };
    hipLaunchCooperativeKernel((const void*)sinkhorn_coop,
                               dim3(B_ * 8), dim3(256), args, 0, stream);

    finred_k<<<1, 64, 0, stream>>>(part2, w, out);
}

// Round 6
// 527.515 us; speedup vs baseline: 8.5311x; 8.5311x over previous
//
#include <hip/hip_runtime.h>
#include <cmath>

#define B_ 64
#define NP 512   // N == M == 512, D == 2

constexpr float L2E  = 1.4426950408889634f;   // log2(e)
constexpr float LN2f = 0.6931471805599453f;

struct EpsList { float e[64]; };

__device__ __forceinline__ float exp2_fast(float v) {
#if __has_builtin(__builtin_amdgcn_exp2f)
    return __builtin_amdgcn_exp2f(v);
#else
    return exp2f(v);
#endif
}
__device__ __forceinline__ float log2_fast(float v) {
#if __has_builtin(__builtin_amdgcn_logf)
    return __builtin_amdgcn_logf(v);
#else
    return log2f(v);
#endif
}

// Cooperative kernel, 512 blocks = B_ x 8, 256 threads (2 blocks/CU — the
// geometry rounds 3 and 5 PROVED co-resident). Block (b, q): q<4 -> f-side
// (rows over x, reduce over y), q>=4 -> g-side. rq = q&3 is a 128-row quarter.
// Thread layout: oct = tid&7 owns j = oct (mod 8); tid>>3 owns 4 consecutive
// rows; one float4 LDS broadcast read serves 4 rows (conflict-free, proven).
//
// Buffers: pure pass-parity. Pass p writes buffer (p&1), reads buffer
// ((p-1)&1). Own-side previous value pv[] lives in registers.
//
// Cross-block sync — the round-5 lesson: NO fences, NO acq/rel. All
// cross-block data moves via RELAXED agent-scope atomics (they bypass L1/L2
// to the L3 coherence point but emit zero cache-maintenance instructions).
// Release ordering comes from __syncthreads()'s s_waitcnt vmcnt(0) (sc1
// stores retire on ack from the coherence point); acquire ordering from the
// spin observation + __syncthreads before dependent loads issue.
// Per-SIDE counters: f-blocks wait only for the 4 g-blocks (and vice versa).
__global__ __launch_bounds__(256, 2) void sinkhorn_coop(
    const float* __restrict__ a, const float* __restrict__ x,
    const float* __restrict__ bb, const float* __restrict__ y,
    float* __restrict__ fA, float* __restrict__ gA,
    float* __restrict__ fB, float* __restrict__ gB,
    unsigned int* __restrict__ bar, float* __restrict__ part2,
    EpsList el, int n_eps)
{
    __shared__ float4 sreg[NP];   // {cx, cy, |c|^2, log2-weight} (pass-invariant)
    __shared__ float4 sd[NP];     // {cx, cy, shp, 0} (rebuilt per pass)
    __shared__ float s_eps[64];
    __shared__ float swred[4];

    const int bid = blockIdx.x;
    const int b   = bid >> 3;
    const int q   = bid & 7;
    const bool gside = q >= 4;
    const int rq  = q & 3;
    const int tid = threadIdx.x;
    const int oct = tid & 7;
    const int rowbase = rq * 128 + (tid >> 3) * 4;
    // per-batch, per-side counters, each on its own 128B line
    unsigned int* own_ctr  = bar + b * 64 + (gside ? 32 : 0);
    unsigned int* othr_ctr = bar + b * 64 + (gside ? 0 : 32);

    if (tid < 64) s_eps[tid] = el.e[tid];

    // ---- one-time staging ----
    const float2* oc2   = (const float2*)(gside ? (x + b * NP * 2) : (y + b * NP * 2));
    const float*  oprob = gside ? (a + b * NP) : (bb + b * NP);
    #pragma unroll
    for (int u2 = 0; u2 < 2; ++u2) {
        int t = tid + u2 * 256;
        float2 c = oc2[t];
        sreg[t] = make_float4(c.x, c.y, fmaf(c.y, c.y, c.x * c.x),
                              L2E * logf(oprob[t]));
    }
    const float* mcoord = gside ? (y + b * NP * 2) : (x + b * NP * 2);
    const float* mprob  = gside ? (bb + b * NP)    : (a + b * NP);
    const float4 rc01 = *(const float4*)(mcoord + rowbase * 2);
    const float4 rc23 = *(const float4*)(mcoord + rowbase * 2 + 4);
    float x0[4] = {rc01.x, rc01.z, rc23.x, rc23.z};
    float x1[4] = {rc01.y, rc01.w, rc23.y, rc23.w};
    float half_n2[4];
    #pragma unroll
    for (int r = 0; r < 4; ++r) half_n2[r] = 0.5f * fmaf(x1[r], x1[r], x0[r] * x0[r]);

    float pv[4];
    const int n_pass = n_eps + 2;
    __syncthreads();

    for (int p = 0; p < n_pass; ++p) {
        const float eps = (p == 0) ? s_eps[0]
                        : (p <= n_eps ? s_eps[p - 1] : s_eps[n_eps - 1]);
        const float inv_eps = 1.0f / eps;
        const float ieL2E = inv_eps * L2E;
        const float nie   = -0.5f * ieL2E;

        // rebuild shp; other-side potential of pass p-1 is in buffer ((p-1)&1)
        float* opot = (gside ? ((p & 1) ? fA : fB)
                             : ((p & 1) ? gA : gB)) + b * NP;
        #pragma unroll
        for (int u2 = 0; u2 < 2; ++u2) {
            int t = tid + u2 * 256;
            float4 sr = sreg[t];
            float pot = (p != 0)
                ? __hip_atomic_load(opot + t, __ATOMIC_RELAXED, __HIP_MEMORY_SCOPE_AGENT)
                : 0.0f;
            float h2 = fmaf(pot, ieL2E, sr.w);
            sd[t] = make_float4(sr.x, sr.y, fmaf(nie, sr.z, h2), 0.0f);
        }
        __syncthreads();

        float x0p[4], x1p[4], m[4], s[4];
        #pragma unroll
        for (int r = 0; r < 4; ++r) {
            x0p[r] = x0[r] * ieL2E;
            x1p[r] = x1[r] * ieL2E;
            m[r] = -INFINITY;
            s[r] = 0.0f;
        }

        #pragma unroll 1
        for (int k = 0; k < 8; ++k) {
            float4 cj[8];
            #pragma unroll
            for (int u2 = 0; u2 < 8; ++u2) cj[u2] = sd[64 * k + 8 * u2 + oct];
            #pragma unroll
            for (int r = 0; r < 4; ++r) {
                float arg[8];
                #pragma unroll
                for (int u2 = 0; u2 < 8; ++u2)
                    arg[u2] = fmaf(x1p[r], cj[u2].y, fmaf(x0p[r], cj[u2].x, cj[u2].z));
                float cm = fmaxf(fmaxf(fmaxf(arg[0], arg[1]), fmaxf(arg[2], arg[3])),
                                 fmaxf(fmaxf(arg[4], arg[5]), fmaxf(arg[6], arg[7])));
                float mn = fmaxf(m[r], cm);
                s[r] *= exp2_fast(m[r] - mn);   // first chunk: exp2(-inf)=0
                #pragma unroll
                for (int u2 = 0; u2 < 8; ++u2) s[r] += exp2_fast(arg[u2] - mn);
                m[r] = mn;
            }
        }

        // combine the 8 octants via butterfly (all lanes end with the result)
        float val[4];
        #pragma unroll
        for (int r = 0; r < 4; ++r) {
            float mr = m[r], sr = s[r];
            #pragma unroll
            for (int d = 1; d <= 4; d <<= 1) {
                float mo = __shfl_xor(mr, d);
                float so = __shfl_xor(sr, d);
                float mt = fmaxf(mr, mo);
                sr = sr * exp2_fast(mr - mt) + so * exp2_fast(mo - mt);
                mr = mt;
            }
            val[r] = fmaf(-eps * LN2f, mr + log2_fast(sr), half_n2[r]);
        }

        if (p >= 1 && p <= n_eps) {
            #pragma unroll
            for (int r = 0; r < 4; ++r) val[r] = 0.5f * (pv[r] + val[r]);
        }
        #pragma unroll
        for (int r = 0; r < 4; ++r) pv[r] = val[r];

        if (p == n_pass - 1) break;   // final extrapolation: no write, no barrier

        if (oct == 0) {
            float* dst = (gside ? ((p & 1) ? gB : gA)
                                : ((p & 1) ? fB : fA)) + b * NP + rowbase;
            #pragma unroll
            for (int r = 0; r < 4; ++r)
                __hip_atomic_store(dst + r, val[r], __ATOMIC_RELAXED,
                                   __HIP_MEMORY_SCOPE_AGENT);
        }

        // ---- per-side handshake (wait only on the 4 other-side blocks) ----
        __syncthreads();   // vmcnt(0): our sc1 stores are visible at L3
        if (tid == 0) {
            __hip_atomic_fetch_add(own_ctr, 1u, __ATOMIC_RELAXED,
                                   __HIP_MEMORY_SCOPE_AGENT);
            const unsigned int target = 4u * (unsigned int)(p + 1);
            unsigned int guard = 0;
            while (__hip_atomic_load(othr_ctr, __ATOMIC_RELAXED,
                                     __HIP_MEMORY_SCOPE_AGENT) < target) {
                __builtin_amdgcn_s_sleep(1);
                if (++guard > (1u << 20)) break;   // valve (never hit if resident)
            }
        }
        __syncthreads();   // others wait for tid0's observation before reading
    }

    // ---- fused weighted dot product of the final extrapolated potentials ----
    float local = 0.0f;
    if (oct == 0) {
        const float4 pr = *(const float4*)(mprob + rowbase);
        local = pr.x * pv[0] + pr.y * pv[1] + pr.z * pv[2] + pr.w * pv[3];
    }
    #pragma unroll
    for (int o = 32; o > 0; o >>= 1) local += __shfl_down(local, o);
    if ((tid & 63) == 0) swred[tid >> 6] = local;
    __syncthreads();
    if (tid == 0) part2[bid] = swred[0] + swred[1] + swred[2] + swred[3];
}

// Deterministic final reduction: out = sum_b w[b] * sum_q part2[b*8+q]
__global__ void finred_k(const float* __restrict__ part2,
                         const float* __restrict__ w, float* __restrict__ out) {
    int b = threadIdx.x;   // 64 threads, one wave
    float s = 0.0f;
    #pragma unroll
    for (int u = 0; u < 8; ++u) s += part2[b * 8 + u];
    s *= w[b];
    #pragma unroll
    for (int o = 32; o > 0; o >>= 1) s += __shfl_down(s, o);
    if (b == 0) out[0] = s;
}

extern "C" void kernel_launch(void* const* d_in, const int* in_sizes, int n_in,
                              void* d_out, int out_size, void* d_ws, size_t ws_size,
                              hipStream_t stream) {
    const float* a  = (const float*)d_in[0];  // prob1   [B,N]
    const float* x  = (const float*)d_in[1];  // coord1  [B,N,2]
    const float* bb = (const float*)d_in[2];  // prob2   [B,M]
    const float* y  = (const float*)d_in[3];  // coord2  [B,M,2]
    const float* w  = (const float*)d_in[4];  // weights [B]
    float* out = (float*)d_out;

    // workspace layout
    unsigned char* wsb = (unsigned char*)d_ws;
    unsigned int* bar = (unsigned int*)wsb;              // 64 x 2 counters, 128B apart
    float* part2 = (float*)(wsb + 64 * 64 * 4);          // 512 floats
    float* fA = (float*)(wsb + 64 * 64 * 4 + 512 * 4);
    const int NB = B_ * NP;
    float* gA = fA + NB;
    float* fB = gA + NB;
    float* gB = fB + NB;

    // eps schedule (geomloss epsilon_schedule semantics, computed in double)
    EpsList el{};
    int n_eps = 0;
    {
        const double start = 2.0 * std::log(4.0);
        const double stop  = 2.0 * std::log(0.01);
        const double step  = 2.0 * std::log(0.9);
        el.e[n_eps++] = 16.0f;                     // DIAMETER**P
        for (int k = 0;; ++k) {
            double v = start + (double)k * step;
            if (!(v > stop)) break;
            el.e[n_eps++] = (float)std::exp(v);
        }
        el.e[n_eps++] = (float)(0.01 * 0.01);      // BLUR**P
    }

    // counters must restart from 0 on every call (ws poisoned once at start)
    hipMemsetAsync(bar, 0, 64 * 64 * 4, stream);

    void* args[] = {
        (void*)&a, (void*)&x, (void*)&bb, (void*)&y,
        (void*)&fA, (void*)&gA, (void*)&fB, (void*)&gB,
        (void*)&bar, (void*)&part2, (void*)&el, (void*)&n_eps
    };
    hipLaunchCooperativeKernel((const void*)sinkhorn_coop,
                               dim3(B_ * 8), dim3(256), args, 0, stream);

    finred_k<<<1, 64, 0, stream>>>(part2, w, out);
}

// Round 8
// 524.871 us; speedup vs baseline: 8.5741x; 1.0050x over previous
//
#include <hip/hip_runtime.h>
#include <cmath>

#define B_ 64
#define NP 512   // N == M == 512, D == 2

constexpr float L2E  = 1.4426950408889634f;   // log2(e)
constexpr float LN2f = 0.6931471805599453f;

typedef float f32x2 __attribute__((ext_vector_type(2)));

struct EpsList { float e[64]; };

__device__ __forceinline__ float exp2_fast(float v) {
#if __has_builtin(__builtin_amdgcn_exp2f)
    return __builtin_amdgcn_exp2f(v);
#else
    return exp2f(v);
#endif
}
__device__ __forceinline__ float log2_fast(float v) {
#if __has_builtin(__builtin_amdgcn_logf)
    return __builtin_amdgcn_logf(v);
#else
    return log2f(v);
#endif
}
__device__ __forceinline__ f32x2 vmax2(f32x2 a, f32x2 b) {
    return __builtin_elementwise_max(a, b);
}

// NORMAL (non-cooperative) persistent launch: 1024 blocks = B_ x 16, 256
// threads, __launch_bounds__(256,4) -> VGPR<=128, LDS ~8.4KB -> 4 blocks/CU
// guaranteed by resources; 1024 = 4 x 256 CUs so the whole grid is resident
// (the guide's sanctioned capacity pattern). Coop launch is NOT used — the
// driver's coop validator rejects >2 blocks/CU (R4/R7 failures).
//
// Block (b, q): q<8 -> f-side (rows over x, reduce over y), q>=8 -> g-side.
// rq = q&7 selects a 64-row slice. Thread layout: sx = tid&15 owns j = sx
// (mod 16), 32 j's per lane; tid>>4 owns 4 consecutive rows. One float4 LDS
// broadcast read serves 4 rows (4 B LDS per row-j, conflict-free).
// Row-paired state packed in f32x2 (v_pk_*_f32); exp2 stays scalar.
//
// Buffers: pure pass-parity (pass p writes buffer p&1, reads (p-1)&1).
// Cross-block sync (R6-proven): RELAXED agent-scope atomics ONLY — no fences,
// no acq/rel (those emit buffer_wbl2/buffer_inv -> R5 coherence storm).
// Release ordering via __syncthreads' s_waitcnt vmcnt(0); per-SIDE counters:
// f-blocks wait only on the 8 g-blocks of their batch and vice versa.
__global__ __launch_bounds__(256, 4) void sinkhorn_pers(
    const float* __restrict__ a, const float* __restrict__ x,
    const float* __restrict__ bb, const float* __restrict__ y,
    float* __restrict__ fA, float* __restrict__ gA,
    float* __restrict__ fB, float* __restrict__ gB,
    unsigned int* __restrict__ bar, float* __restrict__ part2,
    EpsList el, int n_eps)
{
    __shared__ float4 sd[NP];     // {cx, cy, shp, 0} (rebuilt per pass)
    __shared__ float s_eps[64];
    __shared__ float swred[4];

    const int bid = blockIdx.x;
    const int b   = bid >> 4;
    const int q   = bid & 15;
    const bool gside = q >= 8;
    const int rq  = q & 7;
    const int tid = threadIdx.x;
    const int sx  = tid & 15;
    const int rowbase = rq * 64 + (tid >> 4) * 4;
    // per-batch, per-side counters, each on its own 128B line
    unsigned int* own_ctr  = bar + b * 64 + (gside ? 32 : 0);
    unsigned int* othr_ctr = bar + b * 64 + (gside ? 0 : 32);

    if (tid < 64) s_eps[tid] = el.e[tid];

    // ---- one-time staging (registers) ----
    // reduced-over side: 2 points per thread
    const float2* oc2   = (const float2*)(gside ? (x + b * NP * 2) : (y + b * NP * 2));
    const float*  oprob = gside ? (a + b * NP) : (bb + b * NP);
    float ocx[2], ocy[2], on2[2], olw[2];
    #pragma unroll
    for (int u = 0; u < 2; ++u) {
        float2 c = oc2[tid + u * 256];
        ocx[u] = c.x; ocy[u] = c.y;
        on2[u] = fmaf(c.y, c.y, c.x * c.x);
        olw[u] = L2E * logf(oprob[tid + u * 256]);
    }
    // row side: 4 rows per thread
    const float* mcoord = gside ? (y + b * NP * 2) : (x + b * NP * 2);
    const float* mprob  = gside ? (bb + b * NP)    : (a + b * NP);
    const float4 rc01 = *(const float4*)(mcoord + rowbase * 2);
    const float4 rc23 = *(const float4*)(mcoord + rowbase * 2 + 4);
    const float x0[4] = {rc01.x, rc01.z, rc23.x, rc23.z};
    const float x1[4] = {rc01.y, rc01.w, rc23.y, rc23.w};
    float half_n2[4];
    #pragma unroll
    for (int r = 0; r < 4; ++r) half_n2[r] = 0.5f * fmaf(x1[r], x1[r], x0[r] * x0[r]);

    float pv[4];
    const int n_pass = n_eps + 2;
    __syncthreads();

    for (int p = 0; p < n_pass; ++p) {
        const float eps = (p == 0) ? s_eps[0]
                        : (p <= n_eps ? s_eps[p - 1] : s_eps[n_eps - 1]);
        const float inv_eps = 1.0f / eps;
        const float ieL2E = inv_eps * L2E;
        const float nie   = -0.5f * ieL2E;

        // rebuild shp; other-side potential of pass p-1 is in buffer ((p-1)&1)
        {
            float* opot = (gside ? ((p & 1) ? fA : fB)
                                 : ((p & 1) ? gA : gB)) + b * NP;
            #pragma unroll
            for (int u = 0; u < 2; ++u) {
                int t = tid + u * 256;
                float pot = (p != 0)
                    ? __hip_atomic_load(opot + t, __ATOMIC_RELAXED, __HIP_MEMORY_SCOPE_AGENT)
                    : 0.0f;
                float h2 = fmaf(pot, ieL2E, olw[u]);
                sd[t] = make_float4(ocx[u], ocy[u], fmaf(nie, on2[u], h2), 0.0f);
            }
        }
        __syncthreads();

        // row-paired packed state: pair 0 = rows {0,1}, pair 1 = rows {2,3}
        f32x2 x0p2[2], x1p2[2], m2[2], s2[2];
        #pragma unroll
        for (int pr = 0; pr < 2; ++pr) {
            x0p2[pr] = (f32x2){x0[2 * pr] * ieL2E, x0[2 * pr + 1] * ieL2E};
            x1p2[pr] = (f32x2){x1[2 * pr] * ieL2E, x1[2 * pr + 1] * ieL2E};
            m2[pr] = (f32x2)(-INFINITY);
            s2[pr] = (f32x2)(0.0f);
        }

        #pragma unroll 1
        for (int k = 0; k < 4; ++k) {
            float4 cj[8];
            #pragma unroll
            for (int u = 0; u < 8; ++u) cj[u] = sd[128 * k + 16 * u + sx];
            #pragma unroll
            for (int pr = 0; pr < 2; ++pr) {
                f32x2 arg[8];
                #pragma unroll
                for (int u = 0; u < 8; ++u) {
                    f32x2 cx2 = cj[u].x;   // scalar splat
                    f32x2 cy2 = cj[u].y;
                    f32x2 cs2 = cj[u].z;
                    arg[u] = x1p2[pr] * cy2 + (x0p2[pr] * cx2 + cs2);
                }
                f32x2 cm = vmax2(vmax2(vmax2(arg[0], arg[1]), vmax2(arg[2], arg[3])),
                                 vmax2(vmax2(arg[4], arg[5]), vmax2(arg[6], arg[7])));
                f32x2 mn = vmax2(m2[pr], cm);
                f32x2 dl = m2[pr] - mn;
                f32x2 e; e.x = exp2_fast(dl.x); e.y = exp2_fast(dl.y);
                s2[pr] *= e;                 // first chunk: 0 * exp2(-inf)=0
                #pragma unroll
                for (int u = 0; u < 8; ++u) {
                    f32x2 t = arg[u] - mn;
                    f32x2 et; et.x = exp2_fast(t.x); et.y = exp2_fast(t.y);
                    s2[pr] += et;
                }
                m2[pr] = mn;
            }
        }

        // combine the 16 j-lanes via butterfly (all lanes end with the result)
        float m[4] = {m2[0].x, m2[0].y, m2[1].x, m2[1].y};
        float s[4] = {s2[0].x, s2[0].y, s2[1].x, s2[1].y};
        float val[4];
        #pragma unroll
        for (int r = 0; r < 4; ++r) {
            float mr = m[r], sr = s[r];
            #pragma unroll
            for (int d = 1; d <= 8; d <<= 1) {
                float mo = __shfl_xor(mr, d);
                float so = __shfl_xor(sr, d);
                float mt = fmaxf(mr, mo);
                sr = sr * exp2_fast(mr - mt) + so * exp2_fast(mo - mt);
                mr = mt;
            }
            val[r] = fmaf(-eps * LN2f, mr + log2_fast(sr), half_n2[r]);
        }

        if (p >= 1 && p <= n_eps) {
            #pragma unroll
            for (int r = 0; r < 4; ++r) val[r] = 0.5f * (pv[r] + val[r]);
        }
        #pragma unroll
        for (int r = 0; r < 4; ++r) pv[r] = val[r];

        if (p == n_pass - 1) break;   // final extrapolation: no write, no barrier

        if (sx == 0) {
            float* dst = (gside ? ((p & 1) ? gB : gA)
                                : ((p & 1) ? fB : fA)) + b * NP + rowbase;
            #pragma unroll
            for (int r = 0; r < 4; ++r)
                __hip_atomic_store(dst + r, val[r], __ATOMIC_RELAXED,
                                   __HIP_MEMORY_SCOPE_AGENT);
        }

        // ---- per-side handshake (wait only on the 8 other-side blocks) ----
        __syncthreads();   // vmcnt(0): our stores are visible at the coherence point
        if (tid == 0) {
            __hip_atomic_fetch_add(own_ctr, 1u, __ATOMIC_RELAXED,
                                   __HIP_MEMORY_SCOPE_AGENT);
            const unsigned int target = 8u * (unsigned int)(p + 1);
            unsigned int guard = 0;
            while (__hip_atomic_load(othr_ctr, __ATOMIC_RELAXED,
                                     __HIP_MEMORY_SCOPE_AGENT) < target) {
                __builtin_amdgcn_s_sleep(1);
                if (++guard > (1u << 20)) break;   // valve (never hit when resident)
            }
        }
        __syncthreads();   // others wait for tid0's observation before reading
    }

    // ---- fused weighted dot product of the final extrapolated potentials ----
    float local = 0.0f;
    if (sx == 0) {
        const float4 pr = *(const float4*)(mprob + rowbase);
        local = pr.x * pv[0] + pr.y * pv[1] + pr.z * pv[2] + pr.w * pv[3];
    }
    #pragma unroll
    for (int o = 32; o > 0; o >>= 1) local += __shfl_down(local, o);
    if ((tid & 63) == 0) swred[tid >> 6] = local;
    __syncthreads();
    if (tid == 0) part2[bid] = swred[0] + swred[1] + swred[2] + swred[3];
}

// Deterministic final reduction: out = sum_b w[b] * sum_q part2[b*16+q]
__global__ void finred_k(const float* __restrict__ part2,
                         const float* __restrict__ w, float* __restrict__ out) {
    int b = threadIdx.x;   // 64 threads, one wave
    float s = 0.0f;
    #pragma unroll
    for (int u = 0; u < 16; ++u) s += part2[b * 16 + u];
    s *= w[b];
    #pragma unroll
    for (int o = 32; o > 0; o >>= 1) s += __shfl_down(s, o);
    if (b == 0) out[0] = s;
}

extern "C" void kernel_launch(void* const* d_in, const int* in_sizes, int n_in,
                              void* d_out, int out_size, void* d_ws, size_t ws_size,
                              hipStream_t stream) {
    const float* a  = (const float*)d_in[0];  // prob1   [B,N]
    const float* x  = (const float*)d_in[1];  // coord1  [B,N,2]
    const float* bb = (const float*)d_in[2];  // prob2   [B,M]
    const float* y  = (const float*)d_in[3];  // coord2  [B,M,2]
    const float* w  = (const float*)d_in[4];  // weights [B]
    float* out = (float*)d_out;

    // workspace layout
    unsigned char* wsb = (unsigned char*)d_ws;
    unsigned int* bar = (unsigned int*)wsb;              // 64 x 2 counters, 128B apart
    float* part2 = (float*)(wsb + 64 * 64 * 4);          // 1024 floats
    float* fA = (float*)(wsb + 64 * 64 * 4 + 1024 * 4);
    const int NB = B_ * NP;
    float* gA = fA + NB;
    float* fB = gA + NB;
    float* gB = fB + NB;

    // eps schedule (geomloss epsilon_schedule semantics, computed in double)
    EpsList el{};
    int n_eps = 0;
    {
        const double start = 2.0 * std::log(4.0);
        const double stop  = 2.0 * std::log(0.01);
        const double step  = 2.0 * std::log(0.9);
        el.e[n_eps++] = 16.0f;                     // DIAMETER**P
        for (int k = 0;; ++k) {
            double v = start + (double)k * step;
            if (!(v > stop)) break;
            el.e[n_eps++] = (float)std::exp(v);
        }
        el.e[n_eps++] = (float)(0.01 * 0.01);      // BLUR**P
    }

    // counters must restart from 0 on every call (ws poisoned once at start)
    hipMemsetAsync(bar, 0, 64 * 64 * 4, stream);

    sinkhorn_pers<<<dim3(B_ * 16), dim3(256), 0, stream>>>(
        a, x, bb, y, fA, gA, fB, gB, bar, part2, el, n_eps);

    finred_k<<<1, 64, 0, stream>>>(part2, w, out);
}

// Round 9
// 506.627 us; speedup vs baseline: 8.8829x; 1.0360x over previous
//
#include <hip/hip_runtime.h>
#include <cmath>

#define B_ 64
#define NP 512   // N == M == 512, D == 2

constexpr float L2E  = 1.4426950408889634f;   // log2(e)
constexpr float LN2f = 0.6931471805599453f;

struct EpsList { float e[64]; };

__device__ __forceinline__ float exp2_fast(float v) {
#if __has_builtin(__builtin_amdgcn_exp2f)
    return __builtin_amdgcn_exp2f(v);
#else
    return exp2f(v);
#endif
}
__device__ __forceinline__ float log2_fast(float v) {
#if __has_builtin(__builtin_amdgcn_logf)
    return __builtin_amdgcn_logf(v);
#else
    return log2f(v);
#endif
}

// NORMAL (non-cooperative) persistent launch: 1024 blocks, 256 threads,
// __launch_bounds__(256,4) -> VGPR<=128, LDS ~8.4KB -> 4 blocks/CU by
// resources; 1024 = 4 x 256 CUs so the whole grid is resident.
//
// Block mapping (the R8 lesson): b = bid & 63, q = bid >> 6 — consecutive
// bids belong to DIFFERENT batches, so the 4 blocks sharing a CU come from 4
// different batches and cross-batch compute fills each batch's sync idle.
// q<8 -> f-side (rows over x, reduce over y), q>=8 -> g-side; rq = q&7 is a
// 64-row slice. sx = tid&15 owns j = sx (mod 16), 32 j's per lane; tid>>4
// owns 4 consecutive rows; one float4 LDS broadcast read serves 4 rows.
// Scalar inner loop (R8 lesson: v_pk_*_f32 is half-rate on gfx950 — packing
// is issue-neutral and adds movs).
//
// Buffers: pure pass-parity (pass p writes buffer p&1, reads (p-1)&1).
// Cross-block sync (R6-proven): RELAXED agent-scope atomics ONLY — no fences,
// no acq/rel (those emit buffer_wbl2/buffer_inv -> R5 coherence storm).
// Release ordering via __syncthreads' s_waitcnt vmcnt(0); per-SIDE counters:
// f-blocks wait only on the 8 g-blocks of their batch and vice versa.
__global__ __launch_bounds__(256, 4) void sinkhorn_pers(
    const float* __restrict__ a, const float* __restrict__ x,
    const float* __restrict__ bb, const float* __restrict__ y,
    float* __restrict__ fA, float* __restrict__ gA,
    float* __restrict__ fB, float* __restrict__ gB,
    unsigned int* __restrict__ bar, float* __restrict__ part2,
    EpsList el, int n_eps)
{
    __shared__ float4 sd[NP];     // {cx, cy, shp, 0} (rebuilt per pass)
    __shared__ float s_eps[64];
    __shared__ float swred[4];

    const int bid = blockIdx.x;
    const int b   = bid & 63;     // batch-interleaved mapping
    const int q   = bid >> 6;
    const bool gside = q >= 8;
    const int rq  = q & 7;
    const int tid = threadIdx.x;
    const int sx  = tid & 15;
    const int rowbase = rq * 64 + (tid >> 4) * 4;
    // per-batch, per-side counters, each on its own 128B line
    unsigned int* own_ctr  = bar + b * 64 + (gside ? 32 : 0);
    unsigned int* othr_ctr = bar + b * 64 + (gside ? 0 : 32);

    if (tid < 64) s_eps[tid] = el.e[tid];

    // ---- one-time staging (registers) ----
    // reduced-over side: 2 points per thread
    const float2* oc2   = (const float2*)(gside ? (x + b * NP * 2) : (y + b * NP * 2));
    const float*  oprob = gside ? (a + b * NP) : (bb + b * NP);
    float ocx[2], ocy[2], on2[2], olw[2];
    #pragma unroll
    for (int u = 0; u < 2; ++u) {
        float2 c = oc2[tid + u * 256];
        ocx[u] = c.x; ocy[u] = c.y;
        on2[u] = fmaf(c.y, c.y, c.x * c.x);
        olw[u] = L2E * logf(oprob[tid + u * 256]);
    }
    // row side: 4 rows per thread
    const float* mcoord = gside ? (y + b * NP * 2) : (x + b * NP * 2);
    const float* mprob  = gside ? (bb + b * NP)    : (a + b * NP);
    const float4 rc01 = *(const float4*)(mcoord + rowbase * 2);
    const float4 rc23 = *(const float4*)(mcoord + rowbase * 2 + 4);
    const float x0[4] = {rc01.x, rc01.z, rc23.x, rc23.z};
    const float x1[4] = {rc01.y, rc01.w, rc23.y, rc23.w};
    float half_n2[4];
    #pragma unroll
    for (int r = 0; r < 4; ++r) half_n2[r] = 0.5f * fmaf(x1[r], x1[r], x0[r] * x0[r]);

    float pv[4];
    const int n_pass = n_eps + 2;
    __syncthreads();

    for (int p = 0; p < n_pass; ++p) {
        const float eps = (p == 0) ? s_eps[0]
                        : (p <= n_eps ? s_eps[p - 1] : s_eps[n_eps - 1]);
        const float inv_eps = 1.0f / eps;
        const float ieL2E = inv_eps * L2E;
        const float nie   = -0.5f * ieL2E;

        // rebuild shp; other-side potential of pass p-1 is in buffer ((p-1)&1)
        {
            float* opot = (gside ? ((p & 1) ? fA : fB)
                                 : ((p & 1) ? gA : gB)) + b * NP;
            #pragma unroll
            for (int u = 0; u < 2; ++u) {
                int t = tid + u * 256;
                float pot = (p != 0)
                    ? __hip_atomic_load(opot + t, __ATOMIC_RELAXED, __HIP_MEMORY_SCOPE_AGENT)
                    : 0.0f;
                float h2 = fmaf(pot, ieL2E, olw[u]);
                sd[t] = make_float4(ocx[u], ocy[u], fmaf(nie, on2[u], h2), 0.0f);
            }
        }
        __syncthreads();

        float x0p[4], x1p[4], m[4], s[4];
        #pragma unroll
        for (int r = 0; r < 4; ++r) {
            x0p[r] = x0[r] * ieL2E;
            x1p[r] = x1[r] * ieL2E;
            m[r] = -INFINITY;
            s[r] = 0.0f;
        }

        #pragma unroll 1
        for (int k = 0; k < 4; ++k) {
            float4 cj[8];
            #pragma unroll
            for (int u = 0; u < 8; ++u) cj[u] = sd[128 * k + 16 * u + sx];
            #pragma unroll
            for (int r = 0; r < 4; ++r) {
                float arg[8];
                #pragma unroll
                for (int u = 0; u < 8; ++u)
                    arg[u] = fmaf(x1p[r], cj[u].y, fmaf(x0p[r], cj[u].x, cj[u].z));
                float cm = fmaxf(fmaxf(fmaxf(arg[0], arg[1]), fmaxf(arg[2], arg[3])),
                                 fmaxf(fmaxf(arg[4], arg[5]), fmaxf(arg[6], arg[7])));
                float mn = fmaxf(m[r], cm);
                s[r] *= exp2_fast(m[r] - mn);   // first chunk: 0*exp2(-inf)=0
                #pragma unroll
                for (int u = 0; u < 8; ++u) s[r] += exp2_fast(arg[u] - mn);
                m[r] = mn;
            }
        }

        // combine the 16 j-lanes via butterfly (all lanes end with the result)
        float val[4];
        #pragma unroll
        for (int r = 0; r < 4; ++r) {
            float mr = m[r], sr = s[r];
            #pragma unroll
            for (int d = 1; d <= 8; d <<= 1) {
                float mo = __shfl_xor(mr, d);
                float so = __shfl_xor(sr, d);
                float mt = fmaxf(mr, mo);
                sr = sr * exp2_fast(mr - mt) + so * exp2_fast(mo - mt);
                mr = mt;
            }
            val[r] = fmaf(-eps * LN2f, mr + log2_fast(sr), half_n2[r]);
        }

        if (p >= 1 && p <= n_eps) {
            #pragma unroll
            for (int r = 0; r < 4; ++r) val[r] = 0.5f * (pv[r] + val[r]);
        }
        #pragma unroll
        for (int r = 0; r < 4; ++r) pv[r] = val[r];

        if (p == n_pass - 1) break;   // final extrapolation: no write, no barrier

        if (sx == 0) {
            float* dst = (gside ? ((p & 1) ? gB : gA)
                                : ((p & 1) ? fB : fA)) + b * NP + rowbase;
            #pragma unroll
            for (int r = 0; r < 4; ++r)
                __hip_atomic_store(dst + r, val[r], __ATOMIC_RELAXED,
                                   __HIP_MEMORY_SCOPE_AGENT);
        }

        // ---- per-side handshake (wait only on the 8 other-side blocks) ----
        __syncthreads();   // vmcnt(0): our stores are visible at the coherence point
        if (tid == 0) {
            __hip_atomic_fetch_add(own_ctr, 1u, __ATOMIC_RELAXED,
                                   __HIP_MEMORY_SCOPE_AGENT);
            const unsigned int target = 8u * (unsigned int)(p + 1);
            unsigned int guard = 0;
            while (__hip_atomic_load(othr_ctr, __ATOMIC_RELAXED,
                                     __HIP_MEMORY_SCOPE_AGENT) < target) {
                __builtin_amdgcn_s_sleep(1);
                if (++guard > (1u << 20)) break;   // valve (never hit when resident)
            }
        }
        __syncthreads();   // others wait for tid0's observation before reading
    }

    // ---- fused weighted dot product of the final extrapolated potentials ----
    float local = 0.0f;
    if (sx == 0) {
        const float4 pr = *(const float4*)(mprob + rowbase);
        local = pr.x * pv[0] + pr.y * pv[1] + pr.z * pv[2] + pr.w * pv[3];
    }
    #pragma unroll
    for (int o = 32; o > 0; o >>= 1) local += __shfl_down(local, o);
    if ((tid & 63) == 0) swred[tid >> 6] = local;
    __syncthreads();
    if (tid == 0) part2[bid] = swred[0] + swred[1] + swred[2] + swred[3];
}

// Deterministic final reduction: out = sum_b w[b] * sum_q part2[q*64+b]
__global__ void finred_k(const float* __restrict__ part2,
                         const float* __restrict__ w, float* __restrict__ out) {
    int b = threadIdx.x;   // 64 threads, one wave
    float s = 0.0f;
    #pragma unroll
    for (int u = 0; u < 16; ++u) s += part2[u * 64 + b];
    s *= w[b];
    #pragma unroll
    for (int o = 32; o > 0; o >>= 1) s += __shfl_down(s, o);
    if (b == 0) out[0] = s;
}

extern "C" void kernel_launch(void* const* d_in, const int* in_sizes, int n_in,
                              void* d_out, int out_size, void* d_ws, size_t ws_size,
                              hipStream_t stream) {
    const float* a  = (const float*)d_in[0];  // prob1   [B,N]
    const float* x  = (const float*)d_in[1];  // coord1  [B,N,2]
    const float* bb = (const float*)d_in[2];  // prob2   [B,M]
    const float* y  = (const float*)d_in[3];  // coord2  [B,M,2]
    const float* w  = (const float*)d_in[4];  // weights [B]
    float* out = (float*)d_out;

    // workspace layout
    unsigned char* wsb = (unsigned char*)d_ws;
    unsigned int* bar = (unsigned int*)wsb;              // 64 x 2 counters, 128B apart
    float* part2 = (float*)(wsb + 64 * 64 * 4);          // 1024 floats
    float* fA = (float*)(wsb + 64 * 64 * 4 + 1024 * 4);
    const int NB = B_ * NP;
    float* gA = fA + NB;
    float* fB = gA + NB;
    float* gB = fB + NB;

    // eps schedule (geomloss epsilon_schedule semantics, computed in double)
    EpsList el{};
    int n_eps = 0;
    {
        const double start = 2.0 * std::log(4.0);
        const double stop  = 2.0 * std::log(0.01);
        const double step  = 2.0 * std::log(0.9);
        el.e[n_eps++] = 16.0f;                     // DIAMETER**P
        for (int k = 0;; ++k) {
            double v = start + (double)k * step;
            if (!(v > stop)) break;
            el.e[n_eps++] = (float)std::exp(v);
        }
        el.e[n_eps++] = (float)(0.01 * 0.01);      // BLUR**P
    }

    // counters must restart from 0 on every call (ws poisoned once at start)
    hipMemsetAsync(bar, 0, 64 * 64 * 4, stream);

    sinkhorn_pers<<<dim3(B_ * 16), dim3(256), 0, stream>>>(
        a, x, bb, y, fA, gA, fB, gB, bar, part2, el, n_eps);

    finred_k<<<1, 64, 0, stream>>>(part2, w, out);
}

// Round 10
// 445.654 us; speedup vs baseline: 10.0982x; 1.1368x over previous
//
#include <hip/hip_runtime.h>
#include <cmath>

#define B_ 64
#define NP 512   // N == M == 512, D == 2

constexpr float L2E  = 1.4426950408889634f;   // log2(e)
constexpr float LN2f = 0.6931471805599453f;

struct EpsList { float e[64]; };

__device__ __forceinline__ float exp2_fast(float v) {
#if __has_builtin(__builtin_amdgcn_exp2f)
    return __builtin_amdgcn_exp2f(v);
#else
    return exp2f(v);
#endif
}
__device__ __forceinline__ float log2_fast(float v) {
#if __has_builtin(__builtin_amdgcn_logf)
    return __builtin_amdgcn_logf(v);
#else
    return log2f(v);
#endif
}
// written so clang fuses to v_max3_f32
__device__ __forceinline__ float max3f(float a, float b, float c) {
    return fmaxf(fmaxf(a, b), c);
}

// NORMAL persistent launch: 1024 blocks, 256 threads, __launch_bounds__(256,4)
// -> 4 blocks/CU by resources; whole grid resident (R8/R9 proven).
//
// Block mapping (R9-proven): b = bid & 63, q = bid >> 6 — the 4 blocks
// sharing a CU come from 4 different batches, so cross-batch compute fills
// each batch's sync idle. q<8 -> f-side, q>=8 -> g-side; rq = q&7 is a
// 64-row slice.
//
// Thread layout (NEW this round): sx = tid&7 owns j = sx (mod 8), 64 j's per
// lane; tid>>3 owns 2 consecutive rows. One float4 LDS broadcast read serves
// 2 rows (8 B LDS per row-j, 8-distinct-address broadcast, conflict-free).
// Rationale: reduction butterfly shrinks to 3 stages x 2 rows, and the
// combine is TWO-PHASE (max-butterfly, single rescale, sum-butterfly) — 1
// exp2 per row instead of 2 per stage. Max trees use v_max3_f32 nests.
//
// Buffers: pure pass-parity (pass p writes buffer p&1, reads (p-1)&1).
// Cross-block sync (R6-proven): RELAXED agent-scope atomics ONLY — no fences,
// no acq/rel (those emit buffer_wbl2/buffer_inv -> R5 coherence storm).
// Release ordering via __syncthreads' s_waitcnt vmcnt(0); per-SIDE counters:
// f-blocks wait only on the 8 g-blocks of their batch and vice versa.
__global__ __launch_bounds__(256, 4) void sinkhorn_pers(
    const float* __restrict__ a, const float* __restrict__ x,
    const float* __restrict__ bb, const float* __restrict__ y,
    float* __restrict__ fA, float* __restrict__ gA,
    float* __restrict__ fB, float* __restrict__ gB,
    unsigned int* __restrict__ bar, float* __restrict__ part2,
    EpsList el, int n_eps)
{
    __shared__ float4 sd[NP];     // {cx, cy, shp, 0} (rebuilt per pass)
    __shared__ float s_eps[64];
    __shared__ float swred[4];

    const int bid = blockIdx.x;
    const int b   = bid & 63;     // batch-interleaved mapping
    const int q   = bid >> 6;
    const bool gside = q >= 8;
    const int rq  = q & 7;
    const int tid = threadIdx.x;
    const int sx  = tid & 7;
    const int rowbase = rq * 64 + (tid >> 3) * 2;   // 2 rows per thread
    // per-batch, per-side counters, each on its own 128B line
    unsigned int* own_ctr  = bar + b * 64 + (gside ? 32 : 0);
    unsigned int* othr_ctr = bar + b * 64 + (gside ? 0 : 32);

    if (tid < 64) s_eps[tid] = el.e[tid];

    // ---- one-time staging (registers) ----
    // reduced-over side: 2 points per thread
    const float2* oc2   = (const float2*)(gside ? (x + b * NP * 2) : (y + b * NP * 2));
    const float*  oprob = gside ? (a + b * NP) : (bb + b * NP);
    float ocx[2], ocy[2], on2[2], olw[2];
    #pragma unroll
    for (int u = 0; u < 2; ++u) {
        float2 c = oc2[tid + u * 256];
        ocx[u] = c.x; ocy[u] = c.y;
        on2[u] = fmaf(c.y, c.y, c.x * c.x);
        olw[u] = L2E * logf(oprob[tid + u * 256]);
    }
    // row side: 2 rows per thread
    const float* mcoord = gside ? (y + b * NP * 2) : (x + b * NP * 2);
    const float* mprob  = gside ? (bb + b * NP)    : (a + b * NP);
    const float4 rc01 = *(const float4*)(mcoord + rowbase * 2);   // rows 0,1
    const float x0[2] = {rc01.x, rc01.z};
    const float x1[2] = {rc01.y, rc01.w};
    float half_n2[2];
    #pragma unroll
    for (int r = 0; r < 2; ++r) half_n2[r] = 0.5f * fmaf(x1[r], x1[r], x0[r] * x0[r]);

    float pv[2];
    const int n_pass = n_eps + 2;
    __syncthreads();

    for (int p = 0; p < n_pass; ++p) {
        const float eps = (p == 0) ? s_eps[0]
                        : (p <= n_eps ? s_eps[p - 1] : s_eps[n_eps - 1]);
        const float inv_eps = 1.0f / eps;
        const float ieL2E = inv_eps * L2E;
        const float nie   = -0.5f * ieL2E;

        // rebuild shp; other-side potential of pass p-1 is in buffer ((p-1)&1)
        {
            float* opot = (gside ? ((p & 1) ? fA : fB)
                                 : ((p & 1) ? gA : gB)) + b * NP;
            #pragma unroll
            for (int u = 0; u < 2; ++u) {
                int t = tid + u * 256;
                float pot = (p != 0)
                    ? __hip_atomic_load(opot + t, __ATOMIC_RELAXED, __HIP_MEMORY_SCOPE_AGENT)
                    : 0.0f;
                float h2 = fmaf(pot, ieL2E, olw[u]);
                sd[t] = make_float4(ocx[u], ocy[u], fmaf(nie, on2[u], h2), 0.0f);
            }
        }
        __syncthreads();

        float x0p[2], x1p[2], m[2], s[2];
        #pragma unroll
        for (int r = 0; r < 2; ++r) {
            x0p[r] = x0[r] * ieL2E;
            x1p[r] = x1[r] * ieL2E;
            m[r] = -INFINITY;
            s[r] = 0.0f;
        }

        #pragma unroll 1
        for (int k = 0; k < 8; ++k) {
            float4 cj[8];
            #pragma unroll
            for (int u = 0; u < 8; ++u) cj[u] = sd[64 * k + 8 * u + sx];
            #pragma unroll
            for (int r = 0; r < 2; ++r) {
                float arg[8];
                #pragma unroll
                for (int u = 0; u < 8; ++u)
                    arg[u] = fmaf(x1p[r], cj[u].y, fmaf(x0p[r], cj[u].x, cj[u].z));
                // v_max3 tree: 4 ops incl. running max
                float t0 = max3f(arg[0], arg[1], arg[2]);
                float t1 = max3f(arg[3], arg[4], arg[5]);
                float t2 = max3f(arg[6], arg[7], m[r]);
                float mn = max3f(t0, t1, t2);
                s[r] *= exp2_fast(m[r] - mn);   // first chunk: 0*exp2(-inf)=0
                #pragma unroll
                for (int u = 0; u < 8; ++u) s[r] += exp2_fast(arg[u] - mn);
                m[r] = mn;
            }
        }

        // two-phase combine across the 8 j-lanes:
        // max-butterfly -> single rescale -> sum-butterfly (1 exp2 per row)
        float val[2];
        #pragma unroll
        for (int r = 0; r < 2; ++r) {
            float mr = m[r];
            #pragma unroll
            for (int d = 1; d <= 4; d <<= 1) mr = fmaxf(mr, __shfl_xor(mr, d));
            float sr = s[r] * exp2_fast(m[r] - mr);
            #pragma unroll
            for (int d = 1; d <= 4; d <<= 1) sr += __shfl_xor(sr, d);
            val[r] = fmaf(-eps * LN2f, mr + log2_fast(sr), half_n2[r]);
        }

        if (p >= 1 && p <= n_eps) {
            #pragma unroll
            for (int r = 0; r < 2; ++r) val[r] = 0.5f * (pv[r] + val[r]);
        }
        #pragma unroll
        for (int r = 0; r < 2; ++r) pv[r] = val[r];

        if (p == n_pass - 1) break;   // final extrapolation: no write, no barrier

        if (sx == 0) {
            float* dst = (gside ? ((p & 1) ? gB : gA)
                                : ((p & 1) ? fB : fA)) + b * NP + rowbase;
            #pragma unroll
            for (int r = 0; r < 2; ++r)
                __hip_atomic_store(dst + r, val[r], __ATOMIC_RELAXED,
                                   __HIP_MEMORY_SCOPE_AGENT);
        }

        // ---- per-side handshake (wait only on the 8 other-side blocks) ----
        __syncthreads();   // vmcnt(0): our stores are visible at the coherence point
        if (tid == 0) {
            __hip_atomic_fetch_add(own_ctr, 1u, __ATOMIC_RELAXED,
                                   __HIP_MEMORY_SCOPE_AGENT);
            const unsigned int target = 8u * (unsigned int)(p + 1);
            unsigned int guard = 0;
            while (__hip_atomic_load(othr_ctr, __ATOMIC_RELAXED,
                                     __HIP_MEMORY_SCOPE_AGENT) < target) {
                __builtin_amdgcn_s_sleep(1);
                if (++guard > (1u << 20)) break;   // valve (never hit when resident)
            }
        }
        __syncthreads();   // others wait for tid0's observation before reading
    }

    // ---- fused weighted dot product of the final extrapolated potentials ----
    float local = 0.0f;
    if (sx == 0) {
        const float2 pr = *(const float2*)(mprob + rowbase);
        local = pr.x * pv[0] + pr.y * pv[1];
    }
    #pragma unroll
    for (int o = 32; o > 0; o >>= 1) local += __shfl_down(local, o);
    if ((tid & 63) == 0) swred[tid >> 6] = local;
    __syncthreads();
    if (tid == 0) part2[bid] = swred[0] + swred[1] + swred[2] + swred[3];
}

// Deterministic final reduction: out = sum_b w[b] * sum_q part2[q*64+b]
__global__ void finred_k(const float* __restrict__ part2,
                         const float* __restrict__ w, float* __restrict__ out) {
    int b = threadIdx.x;   // 64 threads, one wave
    float s = 0.0f;
    #pragma unroll
    for (int u = 0; u < 16; ++u) s += part2[u * 64 + b];
    s *= w[b];
    #pragma unroll
    for (int o = 32; o > 0; o >>= 1) s += __shfl_down(s, o);
    if (b == 0) out[0] = s;
}

extern "C" void kernel_launch(void* const* d_in, const int* in_sizes, int n_in,
                              void* d_out, int out_size, void* d_ws, size_t ws_size,
                              hipStream_t stream) {
    const float* a  = (const float*)d_in[0];  // prob1   [B,N]
    const float* x  = (const float*)d_in[1];  // coord1  [B,N,2]
    const float* bb = (const float*)d_in[2];  // prob2   [B,M]
    const float* y  = (const float*)d_in[3];  // coord2  [B,M,2]
    const float* w  = (const float*)d_in[4];  // weights [B]
    float* out = (float*)d_out;

    // workspace layout
    unsigned char* wsb = (unsigned char*)d_ws;
    unsigned int* bar = (unsigned int*)wsb;              // 64 x 2 counters, 128B apart
    float* part2 = (float*)(wsb + 64 * 64 * 4);          // 1024 floats
    float* fA = (float*)(wsb + 64 * 64 * 4 + 1024 * 4);
    const int NB = B_ * NP;
    float* gA = fA + NB;
    float* fB = gA + NB;
    float* gB = fB + NB;

    // eps schedule (geomloss epsilon_schedule semantics, computed in double)
    EpsList el{};
    int n_eps = 0;
    {
        const double start = 2.0 * std::log(4.0);
        const double stop  = 2.0 * std::log(0.01);
        const double step  = 2.0 * std::log(0.9);
        el.e[n_eps++] = 16.0f;                     // DIAMETER**P
        for (int k = 0;; ++k) {
            double v = start + (double)k * step;
            if (!(v > stop)) break;
            el.e[n_eps++] = (float)std::exp(v);
        }
        el.e[n_eps++] = (float)(0.01 * 0.01);      // BLUR**P
    }

    // counters must restart from 0 on every call (ws poisoned once at start)
    hipMemsetAsync(bar, 0, 64 * 64 * 4, stream);

    sinkhorn_pers<<<dim3(B_ * 16), dim3(256), 0, stream>>>(
        a, x, bb, y, fA, gA, fB, gB, bar, part2, el, n_eps);

    finred_k<<<1, 64, 0, stream>>>(part2, w, out);
}